// Round 3
// baseline (147.625 us; speedup 1.0000x reference)
//
#include <hip/hip_runtime.h>
#include <hip/hip_bf16.h>
#include <stdint.h>

#define BB 4
#define NN 2048
#define FF 128

typedef __attribute__((ext_vector_type(8))) short bf16x8;
typedef __attribute__((ext_vector_type(4))) float f32x4;

__device__ inline unsigned pk_bf16(float a, float b) {
    union { float f; unsigned u; } x, y;
    x.f = a; y.f = b;
    unsigned xu = x.u + (0x7fffu + ((x.u >> 16) & 1u));
    unsigned yu = y.u + (0x7fffu + ((y.u >> 16) & 1u));
    return (xu >> 16) | (yu & 0xffff0000u);
}

#define XT_P 136
#define WT_P 136

// ---------------- Kernel 1: h = x@W via bf16 MFMA, s = h@a_w + a_b, Ht bf16 ---------
// (unchanged — verified)
__global__ __launch_bounds__(256) void k1_proj(
    const float* __restrict__ x, const float* __restrict__ W,
    const float* __restrict__ a_w, const float* __restrict__ a_b,
    uint16_t* __restrict__ Ht, float* __restrict__ s_out)
{
    __shared__ uint16_t xt[16 * XT_P];
    __shared__ uint16_t Wt[128 * WT_P];
    __shared__ float sredw[4 * 16];

    const int t = threadIdx.x;
    const int w = t >> 6, l = t & 63;
    const int m16 = l & 15, q = l >> 4;
    const int b = blockIdx.x >> 7;
    const int n0 = (blockIdx.x & 127) << 4;

    const int c4 = (t & 31) * 4, kh = (t >> 5) * 16;
    float4 wr0[8], wr1[8];
    #pragma unroll
    for (int kk = 0; kk < 8; ++kk) {
        const int k = kh + 2 * kk;
        wr0[kk] = *(const float4*)(W + (size_t)k * 128 + c4);
        wr1[kk] = *(const float4*)(W + (size_t)(k + 1) * 128 + c4);
    }
    {
        const int row = t >> 4, c0 = (t & 15) * 8;
        const float* xr = x + ((size_t)(b * NN + n0 + row)) * FF + c0;
        const float4 v0 = *(const float4*)xr;
        const float4 v1 = *(const float4*)(xr + 4);
        unsigned* dst = (unsigned*)(xt + row * XT_P + c0);
        dst[0] = pk_bf16(v0.x, v0.y); dst[1] = pk_bf16(v0.z, v0.w);
        dst[2] = pk_bf16(v1.x, v1.y); dst[3] = pk_bf16(v1.z, v1.w);
    }
    #pragma unroll
    for (int kk = 0; kk < 8; ++kk) {
        const int k = kh + 2 * kk;
        *(unsigned*)(Wt + (c4 + 0) * WT_P + k) = pk_bf16(wr0[kk].x, wr1[kk].x);
        *(unsigned*)(Wt + (c4 + 1) * WT_P + k) = pk_bf16(wr0[kk].y, wr1[kk].y);
        *(unsigned*)(Wt + (c4 + 2) * WT_P + k) = pk_bf16(wr0[kk].z, wr1[kk].z);
        *(unsigned*)(Wt + (c4 + 3) * WT_P + k) = pk_bf16(wr0[kk].w, wr1[kk].w);
    }
    const int g0 = (2 * w) * 16 + m16, g1 = (2 * w + 1) * 16 + m16;
    const float aw0 = a_w[g0], aw1 = a_w[g1];
    __syncthreads();

    f32x4 acc0 = {}, acc1 = {};
    bf16x8 af[4];
    #pragma unroll
    for (int dk = 0; dk < 4; ++dk)
        af[dk] = *(const bf16x8*)(xt + m16 * XT_P + dk * 32 + q * 8);
    #pragma unroll
    for (int dk = 0; dk < 4; ++dk) {
        bf16x8 b0 = *(const bf16x8*)(Wt + g0 * WT_P + dk * 32 + q * 8);
        bf16x8 b1 = *(const bf16x8*)(Wt + g1 * WT_P + dk * 32 + q * 8);
        acc0 = __builtin_amdgcn_mfma_f32_16x16x32_bf16(af[dk], b0, acc0, 0, 0, 0);
        acc1 = __builtin_amdgcn_mfma_f32_16x16x32_bf16(af[dk], b1, acc1, 0, 0, 0);
    }

    float sp[4];
    #pragma unroll
    for (int r = 0; r < 4; ++r) sp[r] = acc0[r] * aw0 + acc1[r] * aw1;
    #pragma unroll
    for (int off = 1; off < 16; off <<= 1)
        #pragma unroll
        for (int r = 0; r < 4; ++r) sp[r] += __shfl_xor(sp[r], off, 64);
    if (m16 == 0) {
        #pragma unroll
        for (int r = 0; r < 4; ++r) sredw[w * 16 + q * 4 + r] = sp[r];
    }
    {
        uint2 o0 = { pk_bf16(acc0[0], acc0[1]), pk_bf16(acc0[2], acc0[3]) };
        uint2 o1 = { pk_bf16(acc1[0], acc1[1]), pk_bf16(acc1[2], acc1[3]) };
        *(uint2*)(Ht + ((size_t)(b * 128 + g0)) * NN + n0 + q * 4) = o0;
        *(uint2*)(Ht + ((size_t)(b * 128 + g1)) * NN + n0 + q * 4) = o1;
    }
    __syncthreads();
    if (t < 16)
        s_out[b * NN + n0 + t] = sredw[t] + sredw[16 + t] + sredw[32 + t] + sredw[48 + t] + a_b[0];
}

// ---------------- Kernel 2: fused full-row attention (8-wave, XCD-pinned) ----------
// Grid: 512 blocks of 512 thr (8 waves) -> 2 blocks/CU, 16 waves/CU (4/SIMD).
// b = blockIdx.x & 3: under round-robin block->XCD dispatch, every block on XCD x
// carries batch x&3 -> Ht[b] (2 MB) is L2-resident per XCD (was: 8 MB working set
// thrashing to L3 -> ~300 MB of L3 traffic = the 50 us).
// Block owns 16 i-rows x full 2048 j. 4 rounds x 2 half-rounds of 256 j; wave w
// handles 32-j chunk w*32 (+256 for half 1). No manual prefetch (compiler was
// sinking it anyway); MLP from 8 indep hf loads + TLP from 4 waves/SIMD.
// O and rowsum accumulate in registers; two-stage LDS reduce at the end
// (waves 4-7 store, waves 0-3 += ) keeps LDS at 33.5 KB; normalize+bias+store f32.
__global__ __launch_bounds__(512, 4) void k2_attn(
    const float* __restrict__ A, const uint16_t* __restrict__ Ht,
    const float* __restrict__ s, const float* __restrict__ bias,
    float* __restrict__ out)
{
    __shared__ float Opw[4][16 * 132];   // stride 132 -> benign 2-way aliasing max
    __shared__ float rsw[8][16];

    const int t = threadIdx.x;
    const int w = t >> 6, l = t & 63;
    const int m16 = l & 15, q = l >> 4;

    const int b  = blockIdx.x & 3;       // XCD-pinned batch
    const int is = blockIdx.x >> 2;
    const int ibase = is * 16;

    const float* sb = s + b * NN;
    const float* Ab = A + (size_t)b * NN * NN;
    const uint16_t* Hb = Ht + (size_t)b * FF * NN;

    const float si = sb[ibase + m16];                  // loop-invariant
    const float* Ar = Ab + (size_t)(ibase + m16) * NN;
    const uint16_t* Hr = Hb + (size_t)m16 * NN;

    const int co = w * 32 + q * 8;   // lane's chunk offset within a 256-j half-window

    f32x4 acc[8];
    #pragma unroll
    for (int gt = 0; gt < 8; ++gt) acc[gt] = (f32x4){0.f, 0.f, 0.f, 0.f};
    float rs = 0.f;

    #pragma unroll
    for (int hr = 0; hr < 8; ++hr) {          // 4 rounds x 2 halves = 8 half-rounds
        const int jc = hr * 256 + co;

        // B-fragments: 8 independent L2-hit loads (16 B/lane each)
        bf16x8 hf[8];
        #pragma unroll
        for (int gt = 0; gt < 8; ++gt)
            hf[gt] = *(const bf16x8*)(Hr + (size_t)(gt * 16) * NN + jc);

        float4 a0 = *(const float4*)(Ar + jc);
        float4 a1 = *(const float4*)(Ar + jc + 4);
        float4 s0 = *(const float4*)(sb + jc);
        float4 s1 = *(const float4*)(sb + jc + 4);

        const float sv[8] = {s0.x, s0.y, s0.z, s0.w, s1.x, s1.y, s1.z, s1.w};
        const float av[8] = {a0.x, a0.y, a0.z, a0.w, a1.x, a1.y, a1.z, a1.w};
        float pv[8];
        #pragma unroll
        for (int j = 0; j < 8; ++j) {
            float e = si + sv[j];
            e = fmaxf(e, 0.2f * e);               // LeakyReLU(0.2)
            pv[j] = __expf(e + av[j]);
            rs += pv[j];
        }
        union { unsigned u[4]; bf16x8 v; } fa;
        #pragma unroll
        for (int j = 0; j < 4; ++j)
            fa.u[j] = pk_bf16(pv[2 * j], pv[2 * j + 1]);

        // 8 MFMAs: this wave's P-chunk (K=32 j's) x all 128 g
        #pragma unroll
        for (int gt = 0; gt < 8; ++gt)
            acc[gt] = __builtin_amdgcn_mfma_f32_16x16x32_bf16(fa.v, hf[gt], acc[gt], 0, 0, 0);
    }

    // ---- cross-wave reduce (two-stage), normalize, bias, store ----
    rs += __shfl_xor(rs, 16, 64);
    rs += __shfl_xor(rs, 32, 64);
    if (q == 0) rsw[w][m16] = rs;

    if (w >= 4) {
        #pragma unroll
        for (int gt = 0; gt < 8; ++gt)
            #pragma unroll
            for (int rr = 0; rr < 4; ++rr)
                Opw[w - 4][(q * 4 + rr) * 132 + gt * 16 + m16] = acc[gt][rr];
    }
    __syncthreads();
    if (w < 4) {
        #pragma unroll
        for (int gt = 0; gt < 8; ++gt)
            #pragma unroll
            for (int rr = 0; rr < 4; ++rr)
                Opw[w][(q * 4 + rr) * 132 + gt * 16 + m16] += acc[gt][rr];
    }
    __syncthreads();

    {
        const int row = t >> 5, k4 = (t & 31) * 4;
        float4 v = {0.f, 0.f, 0.f, 0.f};
        #pragma unroll
        for (int sl = 0; sl < 4; ++sl) {
            float4 u = *(const float4*)&Opw[sl][row * 132 + k4];
            v.x += u.x; v.y += u.y; v.z += u.z; v.w += u.w;
        }
        float rst = 0.f;
        #pragma unroll
        for (int sl = 0; sl < 8; ++sl) rst += rsw[sl][row];
        const float inv = 1.0f / rst;
        const float4 bv = *(const float4*)(bias + k4);
        float4 o = { v.x * inv + bv.x, v.y * inv + bv.y,
                     v.z * inv + bv.z, v.w * inv + bv.w };
        *(float4*)(out + ((size_t)(b * NN + ibase + row)) * FF + k4) = o;
    }
}

extern "C" void kernel_launch(void* const* d_in, const int* in_sizes, int n_in,
                              void* d_out, int out_size, void* d_ws, size_t ws_size,
                              hipStream_t stream) {
    const float* x    = (const float*)d_in[0];
    const float* A    = (const float*)d_in[1];
    const float* W    = (const float*)d_in[2];
    const float* a_w  = (const float*)d_in[3];
    const float* a_b  = (const float*)d_in[4];
    const float* bias = (const float*)d_in[5];
    float* out = (float*)d_out;

    char* ws = (char*)d_ws;
    uint16_t* Ht = (uint16_t*)ws;                   // 2 MB
    float* s = (float*)(ws + 2 * 1024 * 1024);      // 32 KB

    k1_proj<<<BB * (NN / 16), 256, 0, stream>>>(x, W, a_w, a_b, Ht, s);
    k2_attn<<<512, 512, 0, stream>>>(A, Ht, s, bias, out);
}

// Round 4
// 127.978 us; speedup vs baseline: 1.1535x; 1.1535x over previous
//
#include <hip/hip_runtime.h>
#include <hip/hip_bf16.h>
#include <stdint.h>

#define BB 4
#define NN 2048
#define FF 128

typedef __attribute__((ext_vector_type(8))) short bf16x8;
typedef __attribute__((ext_vector_type(4))) float f32x4;

__device__ inline unsigned pk_bf16(float a, float b) {
    union { float f; unsigned u; } x, y;
    x.f = a; y.f = b;
    unsigned xu = x.u + (0x7fffu + ((x.u >> 16) & 1u));
    unsigned yu = y.u + (0x7fffu + ((y.u >> 16) & 1u));
    return (xu >> 16) | (yu & 0xffff0000u);
}

#define XT_P 136
#define WT_P 136

// ---------------- Kernel 1: h = x@W via bf16 MFMA, s = h@a_w + a_b, Ht bf16 ---------
// (unchanged — verified)
__global__ __launch_bounds__(256) void k1_proj(
    const float* __restrict__ x, const float* __restrict__ W,
    const float* __restrict__ a_w, const float* __restrict__ a_b,
    uint16_t* __restrict__ Ht, float* __restrict__ s_out)
{
    __shared__ uint16_t xt[16 * XT_P];
    __shared__ uint16_t Wt[128 * WT_P];
    __shared__ float sredw[4 * 16];

    const int t = threadIdx.x;
    const int w = t >> 6, l = t & 63;
    const int m16 = l & 15, q = l >> 4;
    const int b = blockIdx.x >> 7;
    const int n0 = (blockIdx.x & 127) << 4;

    const int c4 = (t & 31) * 4, kh = (t >> 5) * 16;
    float4 wr0[8], wr1[8];
    #pragma unroll
    for (int kk = 0; kk < 8; ++kk) {
        const int k = kh + 2 * kk;
        wr0[kk] = *(const float4*)(W + (size_t)k * 128 + c4);
        wr1[kk] = *(const float4*)(W + (size_t)(k + 1) * 128 + c4);
    }
    {
        const int row = t >> 4, c0 = (t & 15) * 8;
        const float* xr = x + ((size_t)(b * NN + n0 + row)) * FF + c0;
        const float4 v0 = *(const float4*)xr;
        const float4 v1 = *(const float4*)(xr + 4);
        unsigned* dst = (unsigned*)(xt + row * XT_P + c0);
        dst[0] = pk_bf16(v0.x, v0.y); dst[1] = pk_bf16(v0.z, v0.w);
        dst[2] = pk_bf16(v1.x, v1.y); dst[3] = pk_bf16(v1.z, v1.w);
    }
    #pragma unroll
    for (int kk = 0; kk < 8; ++kk) {
        const int k = kh + 2 * kk;
        *(unsigned*)(Wt + (c4 + 0) * WT_P + k) = pk_bf16(wr0[kk].x, wr1[kk].x);
        *(unsigned*)(Wt + (c4 + 1) * WT_P + k) = pk_bf16(wr0[kk].y, wr1[kk].y);
        *(unsigned*)(Wt + (c4 + 2) * WT_P + k) = pk_bf16(wr0[kk].z, wr1[kk].z);
        *(unsigned*)(Wt + (c4 + 3) * WT_P + k) = pk_bf16(wr0[kk].w, wr1[kk].w);
    }
    const int g0 = (2 * w) * 16 + m16, g1 = (2 * w + 1) * 16 + m16;
    const float aw0 = a_w[g0], aw1 = a_w[g1];
    __syncthreads();

    f32x4 acc0 = {}, acc1 = {};
    bf16x8 af[4];
    #pragma unroll
    for (int dk = 0; dk < 4; ++dk)
        af[dk] = *(const bf16x8*)(xt + m16 * XT_P + dk * 32 + q * 8);
    #pragma unroll
    for (int dk = 0; dk < 4; ++dk) {
        bf16x8 b0 = *(const bf16x8*)(Wt + g0 * WT_P + dk * 32 + q * 8);
        bf16x8 b1 = *(const bf16x8*)(Wt + g1 * WT_P + dk * 32 + q * 8);
        acc0 = __builtin_amdgcn_mfma_f32_16x16x32_bf16(af[dk], b0, acc0, 0, 0, 0);
        acc1 = __builtin_amdgcn_mfma_f32_16x16x32_bf16(af[dk], b1, acc1, 0, 0, 0);
    }

    float sp[4];
    #pragma unroll
    for (int r = 0; r < 4; ++r) sp[r] = acc0[r] * aw0 + acc1[r] * aw1;
    #pragma unroll
    for (int off = 1; off < 16; off <<= 1)
        #pragma unroll
        for (int r = 0; r < 4; ++r) sp[r] += __shfl_xor(sp[r], off, 64);
    if (m16 == 0) {
        #pragma unroll
        for (int r = 0; r < 4; ++r) sredw[w * 16 + q * 4 + r] = sp[r];
    }
    {
        uint2 o0 = { pk_bf16(acc0[0], acc0[1]), pk_bf16(acc0[2], acc0[3]) };
        uint2 o1 = { pk_bf16(acc1[0], acc1[1]), pk_bf16(acc1[2], acc1[3]) };
        *(uint2*)(Ht + ((size_t)(b * 128 + g0)) * NN + n0 + q * 4) = o0;
        *(uint2*)(Ht + ((size_t)(b * 128 + g1)) * NN + n0 + q * 4) = o1;
    }
    __syncthreads();
    if (t < 16)
        s_out[b * NN + n0 + t] = sredw[t] + sredw[16 + t] + sredw[32 + t] + sredw[48 + t] + a_b[0];
}

// ---------------- Kernel 2: register-resident split-K attention ----------------------
// Round-0 verified skeleton (h-frags loaded ONCE per block and held in 64 VGPR;
// A streamed with full-round register prefetch), with IRND 8->4: grid js(8) x
// is(32) x b(4) = 1024 blocks -> 4 blocks/CU resident (was 2, grid-limited at
// 17.9% occupancy). Per-round code byte-identical to the verified version.
#define JS 8
#define IRND 4

__global__ __launch_bounds__(256, 2) void k2_attn(
    const float* __restrict__ A, const uint16_t* __restrict__ Ht,
    const float* __restrict__ s, uint16_t* __restrict__ po,
    float* __restrict__ prs)
{
    __shared__ float Opw[4][16 * 132];
    __shared__ float rsw[4][16];

    const int t = threadIdx.x;
    const int w = t >> 6, l = t & 63;
    const int m16 = l & 15, q = l >> 4;

    const int bx = blockIdx.x;
    const int js = bx & 7;
    const int is = (bx >> 3) & 31;
    const int b  = bx >> 8;
    const int j0 = js * 256;
    const int ibase = is * 64;

    const float* sb = s + b * NN;
    const float* Ab = A + (size_t)b * NN * NN;
    const uint16_t* Hb = Ht + (size_t)b * FF * NN;

    const int jc0 = j0 + w * 32 + q * 8;
    const int jc1 = j0 + (w + 4) * 32 + q * 8;

    // loop-invariant sj (16 values per lane)
    float4 sj00 = *(const float4*)(sb + jc0);
    float4 sj01 = *(const float4*)(sb + jc0 + 4);
    float4 sj10 = *(const float4*)(sb + jc1);
    float4 sj11 = *(const float4*)(sb + jc1 + 4);

    // h-fragments in registers: 2 chunks x 8 g-tiles (64 VGPR), held all rounds
    bf16x8 hf0[8], hf1[8];
    #pragma unroll
    for (int gt = 0; gt < 8; ++gt) {
        const uint16_t* hp = Hb + (size_t)(gt * 16 + m16) * NN;
        hf0[gt] = *(const bf16x8*)(hp + jc0);
        hf1[gt] = *(const bf16x8*)(hp + jc1);
    }

    // round-0 A prefetch (lane: row ibase+m16, its 16 j's)
    const float* Ar = Ab + (size_t)(ibase + m16) * NN;
    float4 a00 = *(const float4*)(Ar + jc0);
    float4 a01 = *(const float4*)(Ar + jc0 + 4);
    float4 a10 = *(const float4*)(Ar + jc1);
    float4 a11 = *(const float4*)(Ar + jc1 + 4);
    float si = sb[ibase + m16];

    const size_t slice = (size_t)(js * BB + b);

    for (int r = 0; r < IRND; ++r) {
        const int i0r = ibase + r * 16;
        const int i0n = ibase + ((r + 1) & (IRND - 1)) * 16;

        // prefetch next round's A + si (full-round latency cover)
        const float* An = Ab + (size_t)(i0n + m16) * NN;
        float4 n00 = *(const float4*)(An + jc0);
        float4 n01 = *(const float4*)(An + jc0 + 4);
        float4 n10 = *(const float4*)(An + jc1);
        float4 n11 = *(const float4*)(An + jc1 + 4);
        const float sin_ = sb[i0n + m16];

        const float svv[16] = {sj00.x,sj00.y,sj00.z,sj00.w, sj01.x,sj01.y,sj01.z,sj01.w,
                               sj10.x,sj10.y,sj10.z,sj10.w, sj11.x,sj11.y,sj11.z,sj11.w};
        const float avv[16] = {a00.x,a00.y,a00.z,a00.w, a01.x,a01.y,a01.z,a01.w,
                               a10.x,a10.y,a10.z,a10.w, a11.x,a11.y,a11.z,a11.w};
        float pv[16]; float rs = 0.f;
        #pragma unroll
        for (int j = 0; j < 16; ++j) {
            float e = si + svv[j];
            e = fmaxf(e, 0.2f * e);               // LeakyReLU(0.2)
            pv[j] = __expf(e + avv[j]);
            rs += pv[j];
        }
        union { unsigned u[4]; bf16x8 v; } fa0, fa1;
        #pragma unroll
        for (int j = 0; j < 4; ++j) {
            fa0.u[j] = pk_bf16(pv[2 * j], pv[2 * j + 1]);
            fa1.u[j] = pk_bf16(pv[8 + 2 * j], pv[9 + 2 * j]);
        }

        // 16 MFMAs: this wave's P x all 128 g (h-frags in regs; 8 indep chains)
        f32x4 acc[8];
        #pragma unroll
        for (int gt = 0; gt < 8; ++gt) {
            f32x4 z = {0.f, 0.f, 0.f, 0.f};
            z = __builtin_amdgcn_mfma_f32_16x16x32_bf16(fa0.v, hf0[gt], z, 0, 0, 0);
            acc[gt] = __builtin_amdgcn_mfma_f32_16x16x32_bf16(fa1.v, hf1[gt], acc[gt] = z, 0, 0, 0);
        }

        // row-sum partials: reduce over q within wave (rows = m16)
        rs += __shfl_xor(rs, 16, 64);
        rs += __shfl_xor(rs, 32, 64);
        if (q == 0) rsw[w][m16] = rs;

        // stage this wave's O partial (stride 132 -> 2-way-max bank aliasing)
        #pragma unroll
        for (int gt = 0; gt < 8; ++gt)
            #pragma unroll
            for (int rr = 0; rr < 4; ++rr)
                Opw[w][(q * 4 + rr) * 132 + gt * 16 + m16] = acc[gt][rr];
        asm volatile("s_waitcnt lgkmcnt(0)\n\ts_barrier" ::: "memory");  // no vmem drain

        // cross-wave reduce + store (unnormalized partials; k3 divides)
        {
            const int row = t >> 4, k8 = (t & 15) * 8;
            float v[8] = {0.f,0.f,0.f,0.f,0.f,0.f,0.f,0.f};
            #pragma unroll
            for (int sl = 0; sl < 4; ++sl) {
                float4 u0 = *(const float4*)&Opw[sl][row * 132 + k8];
                float4 u1 = *(const float4*)&Opw[sl][row * 132 + k8 + 4];
                v[0] += u0.x; v[1] += u0.y; v[2] += u0.z; v[3] += u0.w;
                v[4] += u1.x; v[5] += u1.y; v[6] += u1.z; v[7] += u1.w;
            }
            unsigned* op = (unsigned*)(po + ((slice * NN + i0r + row) * FF + k8));
            op[0] = pk_bf16(v[0], v[1]); op[1] = pk_bf16(v[2], v[3]);
            op[2] = pk_bf16(v[4], v[5]); op[3] = pk_bf16(v[6], v[7]);
            if (t < 16)
                prs[slice * NN + i0r + t] = rsw[0][t] + rsw[1][t] + rsw[2][t] + rsw[3][t];
        }
        asm volatile("s_waitcnt lgkmcnt(0)\n\ts_barrier" ::: "memory");  // Opw/rsw reuse

        a00 = n00; a01 = n01; a10 = n10; a11 = n11; si = sin_;
    }
}

// ---------------- Kernel 3: reduce 8 partials, normalize, bias (vectorized) ---------
// Thread handles 8 consecutive g: uint4 po loads (8 bf16, coalesced 256B/16 lanes),
// float4 out stores. Same math as verified scalar version.
__global__ __launch_bounds__(256) void k3_red(
    const uint16_t* __restrict__ po, const float* __restrict__ prs,
    const float* __restrict__ bias, float* __restrict__ out)
{
    const int gid = blockIdx.x * 256 + threadIdx.x;
    const int g8 = (gid & 15) * 8;
    const int i = (gid >> 4) & (NN - 1);
    const int b = gid >> 15;                       // NN*16 threads per batch

    float v[8] = {0.f,0.f,0.f,0.f,0.f,0.f,0.f,0.f};
    float rsum = 0.f;
    #pragma unroll
    for (int js = 0; js < JS; ++js) {
        const size_t base = (size_t)(js * BB + b) * NN + i;
        const uint4 pv_ = *(const uint4*)(po + base * FF + g8);
        const unsigned uu[4] = {pv_.x, pv_.y, pv_.z, pv_.w};
        #pragma unroll
        for (int k = 0; k < 4; ++k) {
            union { unsigned u; float f; } lo, hi;
            lo.u = uu[k] << 16;
            hi.u = uu[k] & 0xffff0000u;
            v[2 * k]     += lo.f;
            v[2 * k + 1] += hi.f;
        }
        rsum += prs[base];
    }
    const float inv = 1.0f / rsum;
    const float4 b0 = *(const float4*)(bias + g8);
    const float4 b1 = *(const float4*)(bias + g8 + 4);
    float4 o0 = { v[0]*inv + b0.x, v[1]*inv + b0.y, v[2]*inv + b0.z, v[3]*inv + b0.w };
    float4 o1 = { v[4]*inv + b1.x, v[5]*inv + b1.y, v[6]*inv + b1.z, v[7]*inv + b1.w };
    float* op = out + ((size_t)(b * NN + i)) * FF + g8;
    *(float4*)op = o0;
    *(float4*)(op + 4) = o1;
}

extern "C" void kernel_launch(void* const* d_in, const int* in_sizes, int n_in,
                              void* d_out, int out_size, void* d_ws, size_t ws_size,
                              hipStream_t stream) {
    const float* x    = (const float*)d_in[0];
    const float* A    = (const float*)d_in[1];
    const float* W    = (const float*)d_in[2];
    const float* a_w  = (const float*)d_in[3];
    const float* a_b  = (const float*)d_in[4];
    const float* bias = (const float*)d_in[5];
    float* out = (float*)d_out;

    char* ws = (char*)d_ws;
    uint16_t* Ht = (uint16_t*)ws;                                  // 2 MB
    float* s = (float*)(ws + 2 * 1024 * 1024);                     // 32 KB (pad to 64K)
    uint16_t* po = (uint16_t*)(ws + 2 * 1024 * 1024 + 65536);      // 16 MB
    float* prs = (float*)(ws + 2 * 1024 * 1024 + 65536 + (size_t)JS * BB * NN * FF * 2);  // 256 KB

    k1_proj<<<BB * (NN / 16), 256, 0, stream>>>(x, W, a_w, a_b, Ht, s);
    k2_attn<<<JS * 32 * BB, 256, 0, stream>>>(A, Ht, s, po, prs);
    k3_red<<<(BB * NN * FF) / (256 * 8), 256, 0, stream>>>(po, prs, bias, out);
}

// Round 5
// 122.673 us; speedup vs baseline: 1.2034x; 1.0432x over previous
//
#include <hip/hip_runtime.h>
#include <hip/hip_bf16.h>
#include <stdint.h>

#define BB 4
#define NN 2048
#define FF 128

typedef __attribute__((ext_vector_type(8))) short bf16x8;
typedef __attribute__((ext_vector_type(4))) float f32x4;

__device__ inline unsigned pk_bf16(float a, float b) {
    union { float f; unsigned u; } x, y;
    x.f = a; y.f = b;
    unsigned xu = x.u + (0x7fffu + ((x.u >> 16) & 1u));
    unsigned yu = y.u + (0x7fffu + ((y.u >> 16) & 1u));
    return (xu >> 16) | (yu & 0xffff0000u);
}

#define XT_P 136
#define WT_P 136

// ---------------- Kernel 1: h = x@W via bf16 MFMA, s = h@a_w + a_b, Ht bf16 ---------
// (unchanged — verified)
__global__ __launch_bounds__(256) void k1_proj(
    const float* __restrict__ x, const float* __restrict__ W,
    const float* __restrict__ a_w, const float* __restrict__ a_b,
    uint16_t* __restrict__ Ht, float* __restrict__ s_out)
{
    __shared__ uint16_t xt[16 * XT_P];
    __shared__ uint16_t Wt[128 * WT_P];
    __shared__ float sredw[4 * 16];

    const int t = threadIdx.x;
    const int w = t >> 6, l = t & 63;
    const int m16 = l & 15, q = l >> 4;
    const int b = blockIdx.x >> 7;
    const int n0 = (blockIdx.x & 127) << 4;

    const int c4 = (t & 31) * 4, kh = (t >> 5) * 16;
    float4 wr0[8], wr1[8];
    #pragma unroll
    for (int kk = 0; kk < 8; ++kk) {
        const int k = kh + 2 * kk;
        wr0[kk] = *(const float4*)(W + (size_t)k * 128 + c4);
        wr1[kk] = *(const float4*)(W + (size_t)(k + 1) * 128 + c4);
    }
    {
        const int row = t >> 4, c0 = (t & 15) * 8;
        const float* xr = x + ((size_t)(b * NN + n0 + row)) * FF + c0;
        const float4 v0 = *(const float4*)xr;
        const float4 v1 = *(const float4*)(xr + 4);
        unsigned* dst = (unsigned*)(xt + row * XT_P + c0);
        dst[0] = pk_bf16(v0.x, v0.y); dst[1] = pk_bf16(v0.z, v0.w);
        dst[2] = pk_bf16(v1.x, v1.y); dst[3] = pk_bf16(v1.z, v1.w);
    }
    #pragma unroll
    for (int kk = 0; kk < 8; ++kk) {
        const int k = kh + 2 * kk;
        *(unsigned*)(Wt + (c4 + 0) * WT_P + k) = pk_bf16(wr0[kk].x, wr1[kk].x);
        *(unsigned*)(Wt + (c4 + 1) * WT_P + k) = pk_bf16(wr0[kk].y, wr1[kk].y);
        *(unsigned*)(Wt + (c4 + 2) * WT_P + k) = pk_bf16(wr0[kk].z, wr1[kk].z);
        *(unsigned*)(Wt + (c4 + 3) * WT_P + k) = pk_bf16(wr0[kk].w, wr1[kk].w);
    }
    const int g0 = (2 * w) * 16 + m16, g1 = (2 * w + 1) * 16 + m16;
    const float aw0 = a_w[g0], aw1 = a_w[g1];
    __syncthreads();

    f32x4 acc0 = {}, acc1 = {};
    bf16x8 af[4];
    #pragma unroll
    for (int dk = 0; dk < 4; ++dk)
        af[dk] = *(const bf16x8*)(xt + m16 * XT_P + dk * 32 + q * 8);
    #pragma unroll
    for (int dk = 0; dk < 4; ++dk) {
        bf16x8 b0 = *(const bf16x8*)(Wt + g0 * WT_P + dk * 32 + q * 8);
        bf16x8 b1 = *(const bf16x8*)(Wt + g1 * WT_P + dk * 32 + q * 8);
        acc0 = __builtin_amdgcn_mfma_f32_16x16x32_bf16(af[dk], b0, acc0, 0, 0, 0);
        acc1 = __builtin_amdgcn_mfma_f32_16x16x32_bf16(af[dk], b1, acc1, 0, 0, 0);
    }

    float sp[4];
    #pragma unroll
    for (int r = 0; r < 4; ++r) sp[r] = acc0[r] * aw0 + acc1[r] * aw1;
    #pragma unroll
    for (int off = 1; off < 16; off <<= 1)
        #pragma unroll
        for (int r = 0; r < 4; ++r) sp[r] += __shfl_xor(sp[r], off, 64);
    if (m16 == 0) {
        #pragma unroll
        for (int r = 0; r < 4; ++r) sredw[w * 16 + q * 4 + r] = sp[r];
    }
    {
        uint2 o0 = { pk_bf16(acc0[0], acc0[1]), pk_bf16(acc0[2], acc0[3]) };
        uint2 o1 = { pk_bf16(acc1[0], acc1[1]), pk_bf16(acc1[2], acc1[3]) };
        *(uint2*)(Ht + ((size_t)(b * 128 + g0)) * NN + n0 + q * 4) = o0;
        *(uint2*)(Ht + ((size_t)(b * 128 + g1)) * NN + n0 + q * 4) = o1;
    }
    __syncthreads();
    if (t < 16)
        s_out[b * NN + n0 + t] = sredw[t] + sredw[16 + t] + sredw[32 + t] + sredw[48 + t] + a_b[0];
}

// ---------------- Kernel 2: register-resident split-K attention ----------------------
// Round-0 verified skeleton: grid js(8) x is(16) x b(4) = 512 blocks (2/CU),
// IRND=8 (128 i-rows/block -> h startup load amortized over 2x the A stream vs
// IRND=4, which measured SLOWER). New: 2-round-deep A/si register prefetch
// (issue-to-use distance ~2 round bodies > HBM latency; extra ~16 VGPR is free
// since occupancy is grid-limited at 2 blocks/CU for any VGPR<=256).
// Round body otherwise byte-identical to the verified round-0 version.
#define JS 8
#define IRND 8

__global__ __launch_bounds__(256, 2) void k2_attn(
    const float* __restrict__ A, const uint16_t* __restrict__ Ht,
    const float* __restrict__ s, uint16_t* __restrict__ po,
    float* __restrict__ prs)
{
    __shared__ float Opw[4][16 * 132];
    __shared__ float rsw[4][16];

    const int t = threadIdx.x;
    const int w = t >> 6, l = t & 63;
    const int m16 = l & 15, q = l >> 4;

    const int bx = blockIdx.x;
    const int js = bx & 7;
    const int is = (bx >> 3) & 15;
    const int b  = bx >> 7;
    const int j0 = js * 256;
    const int ibase = is * 128;

    const float* sb = s + b * NN;
    const float* Ab = A + (size_t)b * NN * NN;
    const uint16_t* Hb = Ht + (size_t)b * FF * NN;

    const int jc0 = j0 + w * 32 + q * 8;
    const int jc1 = j0 + (w + 4) * 32 + q * 8;

    // loop-invariant sj (16 values per lane)
    float4 sj00 = *(const float4*)(sb + jc0);
    float4 sj01 = *(const float4*)(sb + jc0 + 4);
    float4 sj10 = *(const float4*)(sb + jc1);
    float4 sj11 = *(const float4*)(sb + jc1 + 4);

    // h-fragments in registers: 2 chunks x 8 g-tiles (64 VGPR), held all rounds
    bf16x8 hf0[8], hf1[8];
    #pragma unroll
    for (int gt = 0; gt < 8; ++gt) {
        const uint16_t* hp = Hb + (size_t)(gt * 16 + m16) * NN;
        hf0[gt] = *(const bf16x8*)(hp + jc0);
        hf1[gt] = *(const bf16x8*)(hp + jc1);
    }

    // 2-deep A/si prefetch: rounds 0 and 1 in flight before the loop
    const float* Ar0 = Ab + (size_t)(ibase + m16) * NN;
    const float* Ar1 = Ab + (size_t)(ibase + 16 + m16) * NN;
    float4 p000 = *(const float4*)(Ar0 + jc0);
    float4 p001 = *(const float4*)(Ar0 + jc0 + 4);
    float4 p010 = *(const float4*)(Ar0 + jc1);
    float4 p011 = *(const float4*)(Ar0 + jc1 + 4);
    float4 p100 = *(const float4*)(Ar1 + jc0);
    float4 p101 = *(const float4*)(Ar1 + jc0 + 4);
    float4 p110 = *(const float4*)(Ar1 + jc1);
    float4 p111 = *(const float4*)(Ar1 + jc1 + 4);
    float si0 = sb[ibase + m16];
    float si1 = sb[ibase + 16 + m16];

    const size_t slice = (size_t)(js * BB + b);

    #pragma unroll
    for (int r = 0; r < IRND; ++r) {
        const int i0r = ibase + r * 16;
        const int i2  = ibase + ((r + 2) & (IRND - 1)) * 16;

        // prefetch round r+2's A + si (2-round latency cover; wraps harmlessly)
        const float* An = Ab + (size_t)(i2 + m16) * NN;
        float4 n00 = *(const float4*)(An + jc0);
        float4 n01 = *(const float4*)(An + jc0 + 4);
        float4 n10 = *(const float4*)(An + jc1);
        float4 n11 = *(const float4*)(An + jc1 + 4);
        const float si2 = sb[i2 + m16];

        const float svv[16] = {sj00.x,sj00.y,sj00.z,sj00.w, sj01.x,sj01.y,sj01.z,sj01.w,
                               sj10.x,sj10.y,sj10.z,sj10.w, sj11.x,sj11.y,sj11.z,sj11.w};
        const float avv[16] = {p000.x,p000.y,p000.z,p000.w, p001.x,p001.y,p001.z,p001.w,
                               p010.x,p010.y,p010.z,p010.w, p011.x,p011.y,p011.z,p011.w};
        float pv[16]; float rs = 0.f;
        #pragma unroll
        for (int j = 0; j < 16; ++j) {
            float e = si0 + svv[j];
            e = fmaxf(e, 0.2f * e);               // LeakyReLU(0.2)
            pv[j] = __expf(e + avv[j]);
            rs += pv[j];
        }
        union { unsigned u[4]; bf16x8 v; } fa0, fa1;
        #pragma unroll
        for (int j = 0; j < 4; ++j) {
            fa0.u[j] = pk_bf16(pv[2 * j], pv[2 * j + 1]);
            fa1.u[j] = pk_bf16(pv[8 + 2 * j], pv[9 + 2 * j]);
        }

        // 16 MFMAs: this wave's P x all 128 g (h-frags in regs; 8 indep chains)
        f32x4 acc[8];
        #pragma unroll
        for (int gt = 0; gt < 8; ++gt) {
            f32x4 z = {0.f, 0.f, 0.f, 0.f};
            z = __builtin_amdgcn_mfma_f32_16x16x32_bf16(fa0.v, hf0[gt], z, 0, 0, 0);
            acc[gt] = __builtin_amdgcn_mfma_f32_16x16x32_bf16(fa1.v, hf1[gt], z, 0, 0, 0);
        }

        // row-sum partials: reduce over q within wave (rows = m16)
        rs += __shfl_xor(rs, 16, 64);
        rs += __shfl_xor(rs, 32, 64);
        if (q == 0) rsw[w][m16] = rs;

        // stage this wave's O partial (stride 132 -> 2-way-max bank aliasing)
        #pragma unroll
        for (int gt = 0; gt < 8; ++gt)
            #pragma unroll
            for (int rr = 0; rr < 4; ++rr)
                Opw[w][(q * 4 + rr) * 132 + gt * 16 + m16] = acc[gt][rr];
        asm volatile("s_waitcnt lgkmcnt(0)\n\ts_barrier" ::: "memory");  // no vmem drain

        // cross-wave reduce + store (unnormalized partials; k3 divides)
        {
            const int row = t >> 4, k8 = (t & 15) * 8;
            float v[8] = {0.f,0.f,0.f,0.f,0.f,0.f,0.f,0.f};
            #pragma unroll
            for (int sl = 0; sl < 4; ++sl) {
                float4 u0 = *(const float4*)&Opw[sl][row * 132 + k8];
                float4 u1 = *(const float4*)&Opw[sl][row * 132 + k8 + 4];
                v[0] += u0.x; v[1] += u0.y; v[2] += u0.z; v[3] += u0.w;
                v[4] += u1.x; v[5] += u1.y; v[6] += u1.z; v[7] += u1.w;
            }
            unsigned* op = (unsigned*)(po + ((slice * NN + i0r + row) * FF + k8));
            op[0] = pk_bf16(v[0], v[1]); op[1] = pk_bf16(v[2], v[3]);
            op[2] = pk_bf16(v[4], v[5]); op[3] = pk_bf16(v[6], v[7]);
            if (t < 16)
                prs[slice * NN + i0r + t] = rsw[0][t] + rsw[1][t] + rsw[2][t] + rsw[3][t];
        }
        asm volatile("s_waitcnt lgkmcnt(0)\n\ts_barrier" ::: "memory");  // Opw/rsw reuse

        // rotate the 2-deep pipeline
        p000 = p100; p001 = p101; p010 = p110; p011 = p111; si0 = si1;
        p100 = n00;  p101 = n01;  p110 = n10;  p111 = n11;  si1 = si2;
    }
}

// ---------------- Kernel 3: reduce 8 partials, normalize, bias (vectorized) ---------
// (verified this round) Thread handles 8 consecutive g: uint4 po loads, float4 stores.
__global__ __launch_bounds__(256) void k3_red(
    const uint16_t* __restrict__ po, const float* __restrict__ prs,
    const float* __restrict__ bias, float* __restrict__ out)
{
    const int gid = blockIdx.x * 256 + threadIdx.x;
    const int g8 = (gid & 15) * 8;
    const int i = (gid >> 4) & (NN - 1);
    const int b = gid >> 15;                       // NN*16 threads per batch

    float v[8] = {0.f,0.f,0.f,0.f,0.f,0.f,0.f,0.f};
    float rsum = 0.f;
    #pragma unroll
    for (int js = 0; js < JS; ++js) {
        const size_t base = (size_t)(js * BB + b) * NN + i;
        const uint4 pv_ = *(const uint4*)(po + base * FF + g8);
        const unsigned uu[4] = {pv_.x, pv_.y, pv_.z, pv_.w};
        #pragma unroll
        for (int k = 0; k < 4; ++k) {
            union { unsigned u; float f; } lo, hi;
            lo.u = uu[k] << 16;
            hi.u = uu[k] & 0xffff0000u;
            v[2 * k]     += lo.f;
            v[2 * k + 1] += hi.f;
        }
        rsum += prs[base];
    }
    const float inv = 1.0f / rsum;
    const float4 b0 = *(const float4*)(bias + g8);
    const float4 b1 = *(const float4*)(bias + g8 + 4);
    float4 o0 = { v[0]*inv + b0.x, v[1]*inv + b0.y, v[2]*inv + b0.z, v[3]*inv + b0.w };
    float4 o1 = { v[4]*inv + b1.x, v[5]*inv + b1.y, v[6]*inv + b1.z, v[7]*inv + b1.w };
    float* op = out + ((size_t)(b * NN + i)) * FF + g8;
    *(float4*)op = o0;
    *(float4*)(op + 4) = o1;
}

extern "C" void kernel_launch(void* const* d_in, const int* in_sizes, int n_in,
                              void* d_out, int out_size, void* d_ws, size_t ws_size,
                              hipStream_t stream) {
    const float* x    = (const float*)d_in[0];
    const float* A    = (const float*)d_in[1];
    const float* W    = (const float*)d_in[2];
    const float* a_w  = (const float*)d_in[3];
    const float* a_b  = (const float*)d_in[4];
    const float* bias = (const float*)d_in[5];
    float* out = (float*)d_out;

    char* ws = (char*)d_ws;
    uint16_t* Ht = (uint16_t*)ws;                                  // 2 MB
    float* s = (float*)(ws + 2 * 1024 * 1024);                     // 32 KB (pad to 64K)
    uint16_t* po = (uint16_t*)(ws + 2 * 1024 * 1024 + 65536);      // 16 MB
    float* prs = (float*)(ws + 2 * 1024 * 1024 + 65536 + (size_t)JS * BB * NN * FF * 2);  // 256 KB

    k1_proj<<<BB * (NN / 16), 256, 0, stream>>>(x, W, a_w, a_b, Ht, s);
    k2_attn<<<JS * 16 * BB, 256, 0, stream>>>(A, Ht, s, po, prs);
    k3_red<<<(BB * NN * FF) / (256 * 8), 256, 0, stream>>>(po, prs, bias, out);
}